// Round 4
// baseline (1546.066 us; speedup 1.0000x reference)
//
#include <hip/hip_runtime.h>
#include <hip/hip_bf16.h>

#define DIM 128
#define NS  12   // SAMPLE

struct SMem {
    float feat[NS][DIM];   // block-uniform feature vectors (also reused in final)
    float agg1[NS][DIM];   // hop-1 level-1 aggregates for this node's 12 neighbors
    float part[NS][2];     // per-wave partial sums for the alpha scalars
    float nwsh[NS];        // neighbor weights for the current aggregate
};

// ---------------------------------------------------------------------------
// One aggregate step, block-cooperative. Thread d owns channel d.
// Barrier contract: safe to call back-to-back; all cross-call LDS reuse is
// separated by this call's two collective barriers.
// ---------------------------------------------------------------------------
__device__ __forceinline__ float aggregate_core(const int d, const float ih,
                                                const float* __restrict__ nbv,
                                                const float* __restrict__ w1c,
                                                const float w2d, SMem& sm) {
#pragma unroll
    for (int s = 0; s < NS; ++s) sm.feat[s][d] = ih * nbv[s];
    __syncthreads();

    // alpha_raw[s] = lrelu(feat[s] @ w1, 0.2) . w2   (one scalar per s)
#pragma unroll 1
    for (int s = 0; s < NS; ++s) {
        float a0 = 0.f, a1 = 0.f, a2 = 0.f, a3 = 0.f;
#pragma unroll
        for (int k = 0; k < DIM; k += 4) {
            a0 = fmaf(sm.feat[s][k + 0], w1c[k + 0], a0);
            a1 = fmaf(sm.feat[s][k + 1], w1c[k + 1], a1);
            a2 = fmaf(sm.feat[s][k + 2], w1c[k + 2], a2);
            a3 = fmaf(sm.feat[s][k + 3], w1c[k + 3], a3);
        }
        float acc = (a0 + a1) + (a2 + a3) + sm.nwsh[s] * w1c[DIM];
        acc = acc > 0.f ? acc : 0.2f * acc;           // leaky_relu(0.2)
        float c = acc * w2d;
#pragma unroll
        for (int off = 32; off > 0; off >>= 1) c += __shfl_down(c, off, 64);
        if ((d & 63) == 0) sm.part[s][d >> 6] = c;
    }
    __syncthreads();

    // softmax over the 12 scalars (redundant per thread, trivial cost)
    float a[NS], m = -1e30f;
#pragma unroll
    for (int s = 0; s < NS; ++s) {
        a[s] = sm.part[s][0] + sm.part[s][1];
        m = fmaxf(m, a[s]);
    }
    float sum = 0.f;
#pragma unroll
    for (int s = 0; s < NS; ++s) { a[s] = __expf(a[s] - m); sum += a[s]; }
    const float inv = 1.f / sum;
    float o = 0.f;
#pragma unroll
    for (int s = 0; s < NS; ++s) o = fmaf(a[s], nbv[s], o);
    return o * inv;
}

// ---------------------------------------------------------------------------
// Fully fused: one block per output node n (3200 total). Zero workspace.
//   agg0   = aggregate(hidden[n],    nh1[n*12 .. +12),          nw0[n])
//   agg1_j = aggregate(nh1[n*12+j],  nh2[(n*12+j)*12 .. +12),   nw1[n*12+j])
//   agg2   = aggregate(agg0,         agg1[0..12),               nw0[n])
//   ah = s0*agg0 + s1*agg2 ; w = sigmoid(h@w3 + ah@w4) ; out = (1-w)h + w*ah
// ---------------------------------------------------------------------------
__global__ __launch_bounds__(128) void fused_kernel(
    const float* __restrict__ hidden, const float* __restrict__ nh1,
    const float* __restrict__ nh2, const float* __restrict__ nw0,
    const float* __restrict__ nw1, const float* __restrict__ w1,
    const float* __restrict__ w2, const float* __restrict__ w3,
    const float* __restrict__ w4, const float* __restrict__ sv,
    float* __restrict__ out) {
    const int n = blockIdx.x;   // node 0..3199
    const int d = threadIdx.x;  // channel 0..127
    __shared__ SMem sm;

    // w1 column d in registers (129 values), reused by all 14 aggregates.
    float w1c[DIM + 1];
#pragma unroll
    for (int k = 0; k <= DIM; ++k) w1c[k] = w1[k * DIM + d];
    const float w2d = w2[d];

    // ---- agg0 -----------------------------------------------------------
    const float ih0 = hidden[n * DIM + d];
    float nbv0[NS];  // nh1 rows n*12+j at channel d; doubles as agg1 items
#pragma unroll
    for (int s = 0; s < NS; ++s) nbv0[s] = nh1[(n * NS + s) * DIM + d];
    if (d < NS) sm.nwsh[d] = nw0[n * NS + d];
    const float agg0 = aggregate_core(d, ih0, nbv0, w1c, w2d, sm);

    // ---- agg1[j], j = 0..11 --------------------------------------------
#pragma unroll 1
    for (int j = 0; j < NS; ++j) {
        const size_t k = (size_t)(n * NS + j);
        float nbv[NS];
#pragma unroll
        for (int s = 0; s < NS; ++s) nbv[s] = nh2[(k * NS + s) * DIM + d];
        if (d < NS) sm.nwsh[d] = nw1[k * NS + d];
        sm.agg1[j][d] = aggregate_core(d, nbv0[j], nbv, w1c, w2d, sm);
    }
    __syncthreads();  // agg1 tile visible to all threads

    // ---- agg2 -----------------------------------------------------------
    float nbv2[NS];
#pragma unroll
    for (int s = 0; s < NS; ++s) nbv2[s] = sm.agg1[s][d];
    if (d < NS) sm.nwsh[d] = nw0[n * NS + d];
    const float agg2 = aggregate_core(d, agg0, nbv2, w1c, w2d, sm);

    // ---- final mix ------------------------------------------------------
    const float ah = sv[0] * agg0 + sv[1] * agg2;
    __syncthreads();  // agg2 call's LDS reads done before feat reuse
    sm.feat[0][d] = ih0;  // hidden vector
    sm.feat[1][d] = ah;   // aggregated vector
    __syncthreads();
    float t0 = 0.f, t1 = 0.f, t2 = 0.f, t3 = 0.f;
#pragma unroll
    for (int k = 0; k < DIM; k += 2) {
        t0 = fmaf(sm.feat[0][k],     w3[k * DIM + d],       t0);
        t1 = fmaf(sm.feat[1][k],     w4[k * DIM + d],       t1);
        t2 = fmaf(sm.feat[0][k + 1], w3[(k + 1) * DIM + d], t2);
        t3 = fmaf(sm.feat[1][k + 1], w4[(k + 1) * DIM + d], t3);
    }
    const float t = (t0 + t1) + (t2 + t3);
    const float w = 1.f / (1.f + __expf(-t));
    out[n * DIM + d] = (1.f - w) * ih0 + w * ah;
}

extern "C" void kernel_launch(void* const* d_in, const int* in_sizes, int n_in,
                              void* d_out, int out_size, void* d_ws, size_t ws_size,
                              hipStream_t stream) {
    const float* hidden = (const float*)d_in[0];  // [64,50,128]
    const float* nh1    = (const float*)d_in[1];  // [64,600,128]
    const float* nh2    = (const float*)d_in[2];  // [64,7200,128]
    const float* nw0    = (const float*)d_in[3];  // [64,50,12]
    const float* nw1    = (const float*)d_in[4];  // [64,600,12]
    const float* w1     = (const float*)d_in[5];  // [129,128]
    const float* w2     = (const float*)d_in[6];  // [128,1]
    const float* w3     = (const float*)d_in[7];  // [128,128]
    const float* w4     = (const float*)d_in[8];  // [128,128]
    const float* sv     = (const float*)d_in[9];  // [2,1]

    fused_kernel<<<3200, 128, 0, stream>>>(hidden, nh1, nh2, nw0, nw1, w1, w2,
                                           w3, w4, sv, (float*)d_out);
}